// Round 1
// baseline (608.266 us; speedup 1.0000x reference)
//
#include <hip/hip_runtime.h>

#define IN_F 128
#define HID_F 96

// ---------- CSR build ----------

__global__ void prep_kernel(const float* __restrict__ stdv, float* __restrict__ rstd) {
    int t = threadIdx.x;
    if (t < IN_F) rstd[t] = 1.0f / stdv[t];
}

__global__ void count_kernel(const int* __restrict__ dst, int* __restrict__ deg, int E) {
    int i = blockIdx.x * blockDim.x + threadIdx.x;
    if (i < E) atomicAdd(&deg[dst[i]], 1);
}

__global__ void dinv_kernel(const int* __restrict__ deg, float* __restrict__ dinv, int n) {
    int i = blockIdx.x * blockDim.x + threadIdx.x;
    if (i < n) dinv[i] = rsqrtf((float)deg[i] + 1.0f);  // +1 self-loop
}

// single-block exclusive scan of deg -> rowoff (N=50K, trivial cost)
__global__ void scan_kernel(const int* __restrict__ cnt, int* __restrict__ rowoff,
                            int n, int total) {
    __shared__ int sums[256];
    int t = threadIdx.x;
    int per = (n + 255) >> 8;
    int s0 = t * per;
    int s1 = min(s0 + per, n);
    int s = 0;
    for (int i = s0; i < s1; ++i) s += cnt[i];
    sums[t] = s;
    __syncthreads();
    if (t == 0) {
        int run = 0;
        for (int i = 0; i < 256; ++i) { int v = sums[i]; sums[i] = run; run += v; }
    }
    __syncthreads();
    int run = sums[t];
    for (int i = s0; i < s1; ++i) { rowoff[i] = run; run += cnt[i]; }
    if (t == 255) rowoff[n] = total;
}

__global__ void scatter_kernel(const int* __restrict__ srcv, const int* __restrict__ dstv,
                               const int* __restrict__ rowoff, int* __restrict__ fill,
                               const float* __restrict__ dinv,
                               int* __restrict__ col, float* __restrict__ w, int E) {
    int i = blockIdx.x * blockDim.x + threadIdx.x;
    if (i < E) {
        int s = srcv[i], d = dstv[i];
        int pos = rowoff[d] + atomicAdd(&fill[d], 1);
        col[pos] = s;
        w[pos] = dinv[s] * dinv[d];
    }
}

// ---------- fp32 GEMM: C[N,96] = A[N,K] @ W[K,96], optional input standardization ----------
// block = 256 threads, tile = 64 nodes x 96 outputs; thread computes 4 nodes x 6 outs.

__global__ __launch_bounds__(256) void gemm_kernel(
        const float* __restrict__ A, const float* __restrict__ W,
        const float* __restrict__ mean, const float* __restrict__ rstd,
        float* __restrict__ C, int n, int K, int norm) {
    __shared__ float As[64][33];   // +1 pad breaks bank aliasing on [node][kk] reads
    __shared__ float Ws[32][96];
    int tid = threadIdx.x;
    int ti = tid >> 4;   // 0..15: node sub-index (same node across 16-lane groups -> coalesced C stores)
    int tj = tid & 15;   // 0..15: output group of 6
    int node0 = blockIdx.x * 64;

    float acc[4][6];
#pragma unroll
    for (int i = 0; i < 4; ++i)
#pragma unroll
        for (int m = 0; m < 6; ++m) acc[i][m] = 0.f;

    for (int k0 = 0; k0 < K; k0 += 32) {
        // stage A chunk: 64 rows x 32 floats = 512 float4, 2 per thread
#pragma unroll
        for (int L = 0; L < 2; ++L) {
            int idx = tid + L * 256;
            int r = idx >> 3, q = idx & 7;
            int g = node0 + r;
            float4 v = make_float4(0.f, 0.f, 0.f, 0.f);
            if (g < n) v = *(const float4*)(A + (long)g * K + k0 + q * 4);
            if (norm) {
                float4 mu = *(const float4*)(mean + k0 + q * 4);
                float4 rs = *(const float4*)(rstd + k0 + q * 4);
                v.x = (v.x - mu.x) * rs.x; v.y = (v.y - mu.y) * rs.y;
                v.z = (v.z - mu.z) * rs.z; v.w = (v.w - mu.w) * rs.w;
            }
            As[r][q * 4 + 0] = v.x; As[r][q * 4 + 1] = v.y;
            As[r][q * 4 + 2] = v.z; As[r][q * 4 + 3] = v.w;
        }
        // stage W chunk: 32 rows x 96 floats = 768 float4, 3 per thread
#pragma unroll
        for (int L = 0; L < 3; ++L) {
            int idx = tid + L * 256;
            int kr = idx / 24, jq = idx % 24;
            float4 v = *(const float4*)(W + (long)(k0 + kr) * 96 + jq * 4);
            Ws[kr][jq * 4 + 0] = v.x; Ws[kr][jq * 4 + 1] = v.y;
            Ws[kr][jq * 4 + 2] = v.z; Ws[kr][jq * 4 + 3] = v.w;
        }
        __syncthreads();
#pragma unroll
        for (int kk = 0; kk < 32; ++kk) {
            float av[4];
            av[0] = As[ti][kk]; av[1] = As[ti + 16][kk];
            av[2] = As[ti + 32][kk]; av[3] = As[ti + 48][kk];
            const float2* wr = (const float2*)&Ws[kk][0];
            float2 w01 = wr[tj * 3 + 0];
            float2 w23 = wr[tj * 3 + 1];
            float2 w45 = wr[tj * 3 + 2];
            float wv[6] = { w01.x, w01.y, w23.x, w23.y, w45.x, w45.y };
#pragma unroll
            for (int i = 0; i < 4; ++i)
#pragma unroll
                for (int m = 0; m < 6; ++m) acc[i][m] += av[i] * wv[m];
        }
        __syncthreads();
    }
#pragma unroll
    for (int i = 0; i < 4; ++i) {
        int g = node0 + ti + 16 * i;
        if (g < n) {
            float* crow = C + (long)g * 96 + tj * 6;
#pragma unroll
            for (int m = 0; m < 6; ++m) crow[m] = acc[i][m];
        }
    }
}

// ---------- pull-based prop: one wave per node, lane = channel ----------
// hout[d][c] = relu?( sum_e w[e]*hin[col[e]][c] + dinv[d]^2*hin[d][c] + bias[c] )

__global__ __launch_bounds__(256) void prop_kernel(
        const float* __restrict__ hin, const int* __restrict__ rowoff,
        const int* __restrict__ col, const float* __restrict__ w,
        const float* __restrict__ dinv, const float* __restrict__ bias,
        float* __restrict__ hout, int n, int do_relu) {
    int wid = (blockIdx.x * blockDim.x + threadIdx.x) >> 6;
    int lane = threadIdx.x & 63;
    if (wid >= n) return;
    int e0 = rowoff[wid], e1 = rowoff[wid + 1];
    float acc0 = 0.f, acc1 = 0.f;
    for (int e = e0; e < e1; ++e) {
        int s = col[e];
        float ww = w[e];
        const float* row = hin + (long)s * HID_F;
        acc0 += ww * row[lane];
        if (lane < 32) acc1 += ww * row[64 + lane];
    }
    float ds = dinv[wid]; ds *= ds;
    const float* rown = hin + (long)wid * HID_F;
    acc0 += ds * rown[lane];
    acc0 += bias[lane];
    if (do_relu) acc0 = fmaxf(acc0, 0.f);
    hout[(long)wid * HID_F + lane] = acc0;
    if (lane < 32) {
        acc1 += ds * rown[64 + lane];
        acc1 += bias[64 + lane];
        if (do_relu) acc1 = fmaxf(acc1, 0.f);
        hout[(long)wid * HID_F + 64 + lane] = acc1;
    }
}

// ---------- prop3 fused with output projection: out[d] = (agg+b3) . Wout[:,1] + bout[1] ----------

__global__ __launch_bounds__(256) void prop_out_kernel(
        const float* __restrict__ hin, const int* __restrict__ rowoff,
        const int* __restrict__ col, const float* __restrict__ w,
        const float* __restrict__ dinv, const float* __restrict__ b3,
        const float* __restrict__ Wout, const float* __restrict__ bout,
        float* __restrict__ out, int n) {
    int wid = (blockIdx.x * blockDim.x + threadIdx.x) >> 6;
    int lane = threadIdx.x & 63;
    if (wid >= n) return;
    int e0 = rowoff[wid], e1 = rowoff[wid + 1];
    float acc0 = 0.f, acc1 = 0.f;
    for (int e = e0; e < e1; ++e) {
        int s = col[e];
        float ww = w[e];
        const float* row = hin + (long)s * HID_F;
        acc0 += ww * row[lane];
        if (lane < 32) acc1 += ww * row[64 + lane];
    }
    float ds = dinv[wid]; ds *= ds;
    const float* rown = hin + (long)wid * HID_F;
    acc0 += ds * rown[lane];
    float v = (acc0 + b3[lane]) * Wout[lane * 2 + 1];
    if (lane < 32) {
        acc1 += ds * rown[64 + lane];
        v += (acc1 + b3[64 + lane]) * Wout[(64 + lane) * 2 + 1];
    }
#pragma unroll
    for (int off = 32; off; off >>= 1) v += __shfl_xor(v, off, 64);
    if (lane == 0) out[wid] = v + bout[1];
}

// ---------- launch ----------

extern "C" void kernel_launch(void* const* d_in, const int* in_sizes, int n_in,
                              void* d_out, int out_size, void* d_ws, size_t ws_size,
                              hipStream_t stream) {
    const float* x    = (const float*)d_in[0];
    const int*   eidx = (const int*)d_in[1];
    // d_in[2] = PQVA_mask: structurally fixed (col 0 masked) -> output = col 1
    const float* mean = (const float*)d_in[3];
    const float* stdv = (const float*)d_in[4];
    const float* W1   = (const float*)d_in[5];
    const float* b1   = (const float*)d_in[6];
    const float* W2   = (const float*)d_in[7];
    const float* b2   = (const float*)d_in[8];
    const float* W3   = (const float*)d_in[9];
    const float* b3   = (const float*)d_in[10];
    const float* Wout = (const float*)d_in[11];
    const float* bout = (const float*)d_in[12];
    float* out = (float*)d_out;

    const int n = in_sizes[0] / IN_F;       // 50000
    const int E = in_sizes[1] / 2;          // 800000
    const int* srcv = eidx;
    const int* dstv = eidx + E;

    char* ws = (char*)d_ws;
    size_t off = 0;
    auto alloc = [&](size_t bytes) -> void* {
        void* p = ws + off;
        off = (off + bytes + 255) & ~(size_t)255;
        return p;
    };
    int*   deg    = (int*)alloc((size_t)n * 4);
    int*   fill   = (int*)alloc((size_t)n * 4);
    int*   rowoff = (int*)alloc(((size_t)n + 1) * 4);
    float* dinv   = (float*)alloc((size_t)n * 4);
    int*   col    = (int*)alloc((size_t)E * 4);
    float* wgt    = (float*)alloc((size_t)E * 4);
    float* rstd   = (float*)alloc(IN_F * 4);
    float* bufA   = (float*)alloc((size_t)n * HID_F * 4);
    float* bufB   = (float*)alloc((size_t)n * HID_F * 4);

    hipMemsetAsync(deg, 0, (size_t)n * 4, stream);
    hipMemsetAsync(fill, 0, (size_t)n * 4, stream);

    prep_kernel<<<1, 128, 0, stream>>>(stdv, rstd);
    count_kernel<<<(E + 255) / 256, 256, 0, stream>>>(dstv, deg, E);
    dinv_kernel<<<(n + 255) / 256, 256, 0, stream>>>(deg, dinv, n);
    scan_kernel<<<1, 256, 0, stream>>>(deg, rowoff, n, E);
    scatter_kernel<<<(E + 255) / 256, 256, 0, stream>>>(srcv, dstv, rowoff, fill, dinv,
                                                        col, wgt, E);

    int gemm_grid = (n + 63) / 64;
    int prop_grid = (int)(((long)n * 64 + 255) / 256);

    // layer 1: GEMM (fused standardization) -> prop+b1+relu
    gemm_kernel<<<gemm_grid, 256, 0, stream>>>(x, W1, mean, rstd, bufA, n, IN_F, 1);
    prop_kernel<<<prop_grid, 256, 0, stream>>>(bufA, rowoff, col, wgt, dinv, b1, bufB, n, 1);
    // layer 2
    gemm_kernel<<<gemm_grid, 256, 0, stream>>>(bufB, W2, nullptr, nullptr, bufA, n, HID_F, 0);
    prop_kernel<<<prop_grid, 256, 0, stream>>>(bufA, rowoff, col, wgt, dinv, b2, bufB, n, 1);
    // layer 3 + fused output projection (column 1 only)
    gemm_kernel<<<gemm_grid, 256, 0, stream>>>(bufB, W3, nullptr, nullptr, bufA, n, HID_F, 0);
    prop_out_kernel<<<prop_grid, 256, 0, stream>>>(bufA, rowoff, col, wgt, dinv, b3,
                                                   Wout, bout, out, n);
}

// Round 2
// 510.176 us; speedup vs baseline: 1.1923x; 1.1923x over previous
//
#include <hip/hip_runtime.h>

#define IN_F 128
#define HID_F 96

// ---------- small prep: rstd, folded wv = W3 @ Wout[:,1], c = b3.Wout[:,1] + bout[1] ----------

__global__ void prep_kernel(const float* __restrict__ stdv, float* __restrict__ rstd,
                            const float* __restrict__ W3, const float* __restrict__ Wout,
                            const float* __restrict__ b3, const float* __restrict__ bout,
                            float* __restrict__ wv, float* __restrict__ cconst) {
    int t = threadIdx.x;
    if (t < IN_F) rstd[t] = 1.0f / stdv[t];
    if (t < HID_F) {
        float s = 0.f;
        for (int j = 0; j < HID_F; ++j) s += W3[t * HID_F + j] * Wout[j * 2 + 1];
        wv[t] = s;
    }
    if (t == 0) {
        float s = 0.f;
        for (int j = 0; j < HID_F; ++j) s += b3[j] * Wout[j * 2 + 1];
        cconst[0] = s + bout[1];
    }
}

// ---------- CSR build ----------

__global__ void count_kernel(const int* __restrict__ dst, int* __restrict__ deg, int E) {
    int i = blockIdx.x * blockDim.x + threadIdx.x;
    if (i < E) atomicAdd(&deg[dst[i]], 1);
}

__global__ void dinv_kernel(const int* __restrict__ deg, float* __restrict__ dinv, int n) {
    int i = blockIdx.x * blockDim.x + threadIdx.x;
    if (i < n) dinv[i] = rsqrtf((float)deg[i] + 1.0f);  // +1 self-loop
}

// single-block exclusive scan of deg -> rowoff (N=50K, trivial cost)
__global__ void scan_kernel(const int* __restrict__ cnt, int* __restrict__ rowoff,
                            int n, int total) {
    __shared__ int sums[256];
    int t = threadIdx.x;
    int per = (n + 255) >> 8;
    int s0 = t * per;
    int s1 = min(s0 + per, n);
    int s = 0;
    for (int i = s0; i < s1; ++i) s += cnt[i];
    sums[t] = s;
    __syncthreads();
    if (t == 0) {
        int run = 0;
        for (int i = 0; i < 256; ++i) { int v = sums[i]; sums[i] = run; run += v; }
    }
    __syncthreads();
    int run = sums[t];
    for (int i = s0; i < s1; ++i) { rowoff[i] = run; run += cnt[i]; }
    if (t == 255) rowoff[n] = total;
}

__global__ void scatter_kernel(const int* __restrict__ srcv, const int* __restrict__ dstv,
                               const int* __restrict__ rowoff, int* __restrict__ fill,
                               const float* __restrict__ dinv,
                               int* __restrict__ col, float* __restrict__ w, int E) {
    int i = blockIdx.x * blockDim.x + threadIdx.x;
    if (i < E) {
        int s = srcv[i], d = dstv[i];
        int pos = rowoff[d] + atomicAdd(&fill[d], 1);
        col[pos] = s;
        w[pos] = dinv[s] * dinv[d];
    }
}

// ---------- fp32 GEMM: C[N,96] = A[N,K] @ W[K,96], optional input standardization ----------

__global__ __launch_bounds__(256) void gemm_kernel(
        const float* __restrict__ A, const float* __restrict__ W,
        const float* __restrict__ mean, const float* __restrict__ rstd,
        float* __restrict__ C, int n, int K, int norm) {
    __shared__ float As[64][33];
    __shared__ float Ws[32][96];
    int tid = threadIdx.x;
    int ti = tid >> 4;
    int tj = tid & 15;
    int node0 = blockIdx.x * 64;

    float acc[4][6];
#pragma unroll
    for (int i = 0; i < 4; ++i)
#pragma unroll
        for (int m = 0; m < 6; ++m) acc[i][m] = 0.f;

    for (int k0 = 0; k0 < K; k0 += 32) {
#pragma unroll
        for (int L = 0; L < 2; ++L) {
            int idx = tid + L * 256;
            int r = idx >> 3, q = idx & 7;
            int g = node0 + r;
            float4 v = make_float4(0.f, 0.f, 0.f, 0.f);
            if (g < n) v = *(const float4*)(A + (long)g * K + k0 + q * 4);
            if (norm) {
                float4 mu = *(const float4*)(mean + k0 + q * 4);
                float4 rs = *(const float4*)(rstd + k0 + q * 4);
                v.x = (v.x - mu.x) * rs.x; v.y = (v.y - mu.y) * rs.y;
                v.z = (v.z - mu.z) * rs.z; v.w = (v.w - mu.w) * rs.w;
            }
            As[r][q * 4 + 0] = v.x; As[r][q * 4 + 1] = v.y;
            As[r][q * 4 + 2] = v.z; As[r][q * 4 + 3] = v.w;
        }
#pragma unroll
        for (int L = 0; L < 3; ++L) {
            int idx = tid + L * 256;
            int kr = idx / 24, jq = idx % 24;
            float4 v = *(const float4*)(W + (long)(k0 + kr) * 96 + jq * 4);
            Ws[kr][jq * 4 + 0] = v.x; Ws[kr][jq * 4 + 1] = v.y;
            Ws[kr][jq * 4 + 2] = v.z; Ws[kr][jq * 4 + 3] = v.w;
        }
        __syncthreads();
#pragma unroll
        for (int kk = 0; kk < 32; ++kk) {
            float av[4];
            av[0] = As[ti][kk]; av[1] = As[ti + 16][kk];
            av[2] = As[ti + 32][kk]; av[3] = As[ti + 48][kk];
            const float2* wr = (const float2*)&Ws[kk][0];
            float2 w01 = wr[tj * 3 + 0];
            float2 w23 = wr[tj * 3 + 1];
            float2 w45 = wr[tj * 3 + 2];
            float wv6[6] = { w01.x, w01.y, w23.x, w23.y, w45.x, w45.y };
#pragma unroll
            for (int i = 0; i < 4; ++i)
#pragma unroll
                for (int m = 0; m < 6; ++m) acc[i][m] += av[i] * wv6[m];
        }
        __syncthreads();
    }
#pragma unroll
    for (int i = 0; i < 4; ++i) {
        int g = node0 + ti + 16 * i;
        if (g < n) {
            float* crow = C + (long)g * 96 + tj * 6;
#pragma unroll
            for (int m = 0; m < 6; ++m) crow[m] = acc[i][m];
        }
    }
}

// ---------- pull-based prop (layer 1): wave per node, lane = channel ----------

__global__ __launch_bounds__(256) void prop_kernel(
        const float* __restrict__ hin, const int* __restrict__ rowoff,
        const int* __restrict__ col, const float* __restrict__ w,
        const float* __restrict__ dinv, const float* __restrict__ bias,
        float* __restrict__ hout, int n) {
    int wid = (blockIdx.x * blockDim.x + threadIdx.x) >> 6;
    int lane = threadIdx.x & 63;
    if (wid >= n) return;
    int e0 = rowoff[wid], e1 = rowoff[wid + 1];
    float acc0 = 0.f, acc1 = 0.f;
    for (int e = e0; e < e1; ++e) {
        int s = col[e];
        float ww = w[e];
        const float* row = hin + (long)s * HID_F;
        acc0 += ww * row[lane];
        if (lane < 32) acc1 += ww * row[64 + lane];
    }
    float ds = dinv[wid]; ds *= ds;
    const float* rown = hin + (long)wid * HID_F;
    acc0 = fmaxf(acc0 + ds * rown[lane] + bias[lane], 0.f);
    hout[(long)wid * HID_F + lane] = acc0;
    if (lane < 32) {
        acc1 = fmaxf(acc1 + ds * rown[64 + lane] + bias[64 + lane], 0.f);
        hout[(long)wid * HID_F + 64 + lane] = acc1;
    }
}

// ---------- prop (layer 2) fused with z = relu(agg+b2) . wv : writes scalar z[node] ----------

__global__ __launch_bounds__(256) void prop_dot_kernel(
        const float* __restrict__ hin, const int* __restrict__ rowoff,
        const int* __restrict__ col, const float* __restrict__ w,
        const float* __restrict__ dinv, const float* __restrict__ bias,
        const float* __restrict__ wv, float* __restrict__ z, int n) {
    int wid = (blockIdx.x * blockDim.x + threadIdx.x) >> 6;
    int lane = threadIdx.x & 63;
    if (wid >= n) return;
    int e0 = rowoff[wid], e1 = rowoff[wid + 1];
    float acc0 = 0.f, acc1 = 0.f;
    for (int e = e0; e < e1; ++e) {
        int s = col[e];
        float ww = w[e];
        const float* row = hin + (long)s * HID_F;
        acc0 += ww * row[lane];
        if (lane < 32) acc1 += ww * row[64 + lane];
    }
    float ds = dinv[wid]; ds *= ds;
    const float* rown = hin + (long)wid * HID_F;
    acc0 = fmaxf(acc0 + ds * rown[lane] + bias[lane], 0.f);
    float v = acc0 * wv[lane];
    if (lane < 32) {
        acc1 = fmaxf(acc1 + ds * rown[64 + lane] + bias[64 + lane], 0.f);
        v += acc1 * wv[64 + lane];
    }
#pragma unroll
    for (int off = 32; off; off >>= 1) v += __shfl_xor(v, off, 64);
    if (lane == 0) z[wid] = v;
}

// ---------- layer-3 prop over scalar z: out[d] = sum w[e]*z[col] + dinv2*z[d] + c ----------

__global__ __launch_bounds__(256) void prop_scalar_kernel(
        const float* __restrict__ z, const int* __restrict__ rowoff,
        const int* __restrict__ col, const float* __restrict__ w,
        const float* __restrict__ dinv, const float* __restrict__ cconst,
        float* __restrict__ out, int n) {
    int i = blockIdx.x * blockDim.x + threadIdx.x;
    if (i >= n) return;
    int e0 = rowoff[i], e1 = rowoff[i + 1];
    float s = 0.f;
    for (int e = e0; e < e1; ++e) s += w[e] * z[col[e]];
    float ds = dinv[i]; ds *= ds;
    out[i] = s + ds * z[i] + cconst[0];
}

// ---------- launch ----------

extern "C" void kernel_launch(void* const* d_in, const int* in_sizes, int n_in,
                              void* d_out, int out_size, void* d_ws, size_t ws_size,
                              hipStream_t stream) {
    const float* x    = (const float*)d_in[0];
    const int*   eidx = (const int*)d_in[1];
    const float* mean = (const float*)d_in[3];
    const float* stdv = (const float*)d_in[4];
    const float* W1   = (const float*)d_in[5];
    const float* b1   = (const float*)d_in[6];
    const float* W2   = (const float*)d_in[7];
    const float* b2   = (const float*)d_in[8];
    const float* W3   = (const float*)d_in[9];
    const float* b3   = (const float*)d_in[10];
    const float* Wout = (const float*)d_in[11];
    const float* bout = (const float*)d_in[12];
    float* out = (float*)d_out;

    const int n = in_sizes[0] / IN_F;       // 50000
    const int E = in_sizes[1] / 2;          // 800000
    const int* srcv = eidx;
    const int* dstv = eidx + E;

    char* ws = (char*)d_ws;
    size_t off = 0;
    auto alloc = [&](size_t bytes) -> void* {
        void* p = ws + off;
        off = (off + bytes + 255) & ~(size_t)255;
        return p;
    };
    int*   deg    = (int*)alloc((size_t)n * 4);
    int*   fill   = (int*)alloc((size_t)n * 4);
    int*   rowoff = (int*)alloc(((size_t)n + 1) * 4);
    float* dinv   = (float*)alloc((size_t)n * 4);
    int*   col    = (int*)alloc((size_t)E * 4);
    float* wgt    = (float*)alloc((size_t)E * 4);
    float* rstd   = (float*)alloc(IN_F * 4);
    float* wv     = (float*)alloc(HID_F * 4);
    float* cconst = (float*)alloc(4);
    float* zbuf   = (float*)alloc((size_t)n * 4);
    float* bufA   = (float*)alloc((size_t)n * HID_F * 4);
    float* bufB   = (float*)alloc((size_t)n * HID_F * 4);

    hipMemsetAsync(deg, 0, (size_t)n * 4, stream);
    hipMemsetAsync(fill, 0, (size_t)n * 4, stream);

    prep_kernel<<<1, 128, 0, stream>>>(stdv, rstd, W3, Wout, b3, bout, wv, cconst);
    count_kernel<<<(E + 255) / 256, 256, 0, stream>>>(dstv, deg, E);
    dinv_kernel<<<(n + 255) / 256, 256, 0, stream>>>(deg, dinv, n);
    scan_kernel<<<1, 256, 0, stream>>>(deg, rowoff, n, E);
    scatter_kernel<<<(E + 255) / 256, 256, 0, stream>>>(srcv, dstv, rowoff, fill, dinv,
                                                        col, wgt, E);

    int gemm_grid = (n + 63) / 64;
    int prop_grid = (int)(((long)n * 64 + 255) / 256);

    // layer 1: GEMM (fused standardization) -> prop+b1+relu
    gemm_kernel<<<gemm_grid, 256, 0, stream>>>(x, W1, mean, rstd, bufA, n, IN_F, 1);
    prop_kernel<<<prop_grid, 256, 0, stream>>>(bufA, rowoff, col, wgt, dinv, b1, bufB, n);
    // layer 2: GEMM -> prop+b2+relu fused with dot(wv) -> scalar z
    gemm_kernel<<<gemm_grid, 256, 0, stream>>>(bufB, W2, nullptr, nullptr, bufA, n, HID_F, 0);
    prop_dot_kernel<<<prop_grid, 256, 0, stream>>>(bufA, rowoff, col, wgt, dinv, b2, wv,
                                                   zbuf, n);
    // layer 3 (folded): scalar prop over z
    prop_scalar_kernel<<<(n + 255) / 256, 256, 0, stream>>>(zbuf, rowoff, col, wgt, dinv,
                                                            cconst, out, n);
}

// Round 3
// 417.311 us; speedup vs baseline: 1.4576x; 1.2225x over previous
//
#include <hip/hip_runtime.h>

#define IN_F 128
#define HID_F 96

// ---------- small prep: rstd, folded wv = W3 @ Wout[:,1], c = b3.Wout[:,1] + bout[1] ----------

__global__ void prep_kernel(const float* __restrict__ stdv, float* __restrict__ rstd,
                            const float* __restrict__ W3, const float* __restrict__ Wout,
                            const float* __restrict__ b3, const float* __restrict__ bout,
                            float* __restrict__ wv, float* __restrict__ cconst) {
    int t = threadIdx.x;
    if (t < IN_F) rstd[t] = 1.0f / stdv[t];
    if (t < HID_F) {
        float s = 0.f;
        for (int j = 0; j < HID_F; ++j) s += W3[t * HID_F + j] * Wout[j * 2 + 1];
        wv[t] = s;
    }
    if (t == 0) {
        float s = 0.f;
        for (int j = 0; j < HID_F; ++j) s += b3[j] * Wout[j * 2 + 1];
        cconst[0] = s + bout[1];
    }
}

// ---------- CSR build ----------

__global__ void count_kernel(const int* __restrict__ dst, int* __restrict__ deg, int E) {
    int i = blockIdx.x * blockDim.x + threadIdx.x;
    if (i < E) atomicAdd(&deg[dst[i]], 1);
}

__global__ void dinv_kernel(const int* __restrict__ deg, float* __restrict__ dinv, int n) {
    int i = blockIdx.x * blockDim.x + threadIdx.x;
    if (i < n) dinv[i] = rsqrtf((float)deg[i] + 1.0f);  // +1 self-loop
}

// single-block exclusive scan of deg -> rowoff (N=50K, trivial cost)
__global__ void scan_kernel(const int* __restrict__ cnt, int* __restrict__ rowoff,
                            int n, int total) {
    __shared__ int sums[256];
    int t = threadIdx.x;
    int per = (n + 255) >> 8;
    int s0 = t * per;
    int s1 = min(s0 + per, n);
    int s = 0;
    for (int i = s0; i < s1; ++i) s += cnt[i];
    sums[t] = s;
    __syncthreads();
    if (t == 0) {
        int run = 0;
        for (int i = 0; i < 256; ++i) { int v = sums[i]; sums[i] = run; run += v; }
    }
    __syncthreads();
    int run = sums[t];
    for (int i = s0; i < s1; ++i) { rowoff[i] = run; run += cnt[i]; }
    if (t == 255) rowoff[n] = total;
}

// packed edge record: .x = src node, .y = float bits of norm weight
__global__ void scatter_kernel(const int* __restrict__ srcv, const int* __restrict__ dstv,
                               const int* __restrict__ rowoff, int* __restrict__ fill,
                               const float* __restrict__ dinv,
                               int2* __restrict__ ecw, int E) {
    int i = blockIdx.x * blockDim.x + threadIdx.x;
    if (i < E) {
        int s = srcv[i], d = dstv[i];
        int pos = rowoff[d] + atomicAdd(&fill[d], 1);
        int2 r;
        r.x = s;
        r.y = __float_as_int(dinv[s] * dinv[d]);
        ecw[pos] = r;
    }
}

// ---------- fp32 GEMM: C[N,96] = A[N,K] @ W[K,96], optional input standardization ----------

__global__ __launch_bounds__(256) void gemm_kernel(
        const float* __restrict__ A, const float* __restrict__ W,
        const float* __restrict__ mean, const float* __restrict__ rstd,
        float* __restrict__ C, int n, int K, int norm) {
    __shared__ float As[64][33];
    __shared__ float Ws[32][96];
    int tid = threadIdx.x;
    int ti = tid >> 4;
    int tj = tid & 15;
    int node0 = blockIdx.x * 64;

    float acc[4][6];
#pragma unroll
    for (int i = 0; i < 4; ++i)
#pragma unroll
        for (int m = 0; m < 6; ++m) acc[i][m] = 0.f;

    for (int k0 = 0; k0 < K; k0 += 32) {
#pragma unroll
        for (int L = 0; L < 2; ++L) {
            int idx = tid + L * 256;
            int r = idx >> 3, q = idx & 7;
            int g = node0 + r;
            float4 v = make_float4(0.f, 0.f, 0.f, 0.f);
            if (g < n) v = *(const float4*)(A + (long)g * K + k0 + q * 4);
            if (norm) {
                float4 mu = *(const float4*)(mean + k0 + q * 4);
                float4 rs = *(const float4*)(rstd + k0 + q * 4);
                v.x = (v.x - mu.x) * rs.x; v.y = (v.y - mu.y) * rs.y;
                v.z = (v.z - mu.z) * rs.z; v.w = (v.w - mu.w) * rs.w;
            }
            As[r][q * 4 + 0] = v.x; As[r][q * 4 + 1] = v.y;
            As[r][q * 4 + 2] = v.z; As[r][q * 4 + 3] = v.w;
        }
#pragma unroll
        for (int L = 0; L < 3; ++L) {
            int idx = tid + L * 256;
            int kr = idx / 24, jq = idx % 24;
            float4 v = *(const float4*)(W + (long)(k0 + kr) * 96 + jq * 4);
            Ws[kr][jq * 4 + 0] = v.x; Ws[kr][jq * 4 + 1] = v.y;
            Ws[kr][jq * 4 + 2] = v.z; Ws[kr][jq * 4 + 3] = v.w;
        }
        __syncthreads();
#pragma unroll
        for (int kk = 0; kk < 32; ++kk) {
            float av[4];
            av[0] = As[ti][kk]; av[1] = As[ti + 16][kk];
            av[2] = As[ti + 32][kk]; av[3] = As[ti + 48][kk];
            const float2* wr = (const float2*)&Ws[kk][0];
            float2 w01 = wr[tj * 3 + 0];
            float2 w23 = wr[tj * 3 + 1];
            float2 w45 = wr[tj * 3 + 2];
            float wv6[6] = { w01.x, w01.y, w23.x, w23.y, w45.x, w45.y };
#pragma unroll
            for (int i = 0; i < 4; ++i)
#pragma unroll
                for (int m = 0; m < 6; ++m) acc[i][m] += av[i] * wv6[m];
        }
        __syncthreads();
    }
#pragma unroll
    for (int i = 0; i < 4; ++i) {
        int g = node0 + ti + 16 * i;
        if (g < n) {
            float* crow = C + (long)g * 96 + tj * 6;
#pragma unroll
            for (int m = 0; m < 6; ++m) crow[m] = acc[i][m];
        }
    }
}

// ---------- pull-based prop (layer 1): wave per node, lane = channel, edge loop x4 ----------

__global__ __launch_bounds__(256) void prop_kernel(
        const float* __restrict__ hin, const int* __restrict__ rowoff,
        const int2* __restrict__ ecw,
        const float* __restrict__ dinv, const float* __restrict__ bias,
        float* __restrict__ hout, int n) {
    int wid = (blockIdx.x * blockDim.x + threadIdx.x) >> 6;
    int lane = threadIdx.x & 63;
    if (wid >= n) return;
    int e0 = rowoff[wid], e1 = rowoff[wid + 1];
    float acc0 = 0.f, acc1 = 0.f;
    bool lo = lane < 32;
    int e = e0;
    for (; e + 4 <= e1; e += 4) {
        int2 c0 = ecw[e + 0], c1 = ecw[e + 1], c2 = ecw[e + 2], c3 = ecw[e + 3];
        const float* r0 = hin + (long)c0.x * HID_F;
        const float* r1 = hin + (long)c1.x * HID_F;
        const float* r2 = hin + (long)c2.x * HID_F;
        const float* r3 = hin + (long)c3.x * HID_F;
        float a0 = r0[lane], a1 = r1[lane], a2 = r2[lane], a3 = r3[lane];
        float b0 = 0.f, b1 = 0.f, b2 = 0.f, b3 = 0.f;
        if (lo) { b0 = r0[64 + lane]; b1 = r1[64 + lane]; b2 = r2[64 + lane]; b3 = r3[64 + lane]; }
        float w0 = __int_as_float(c0.y), w1 = __int_as_float(c1.y);
        float w2 = __int_as_float(c2.y), w3 = __int_as_float(c3.y);
        acc0 += w0 * a0; acc0 += w1 * a1; acc0 += w2 * a2; acc0 += w3 * a3;
        acc1 += w0 * b0; acc1 += w1 * b1; acc1 += w2 * b2; acc1 += w3 * b3;
    }
    for (; e < e1; ++e) {
        int2 c = ecw[e];
        const float* row = hin + (long)c.x * HID_F;
        float ww = __int_as_float(c.y);
        acc0 += ww * row[lane];
        if (lo) acc1 += ww * row[64 + lane];
    }
    float ds = dinv[wid]; ds *= ds;
    const float* rown = hin + (long)wid * HID_F;
    acc0 = fmaxf(acc0 + ds * rown[lane] + bias[lane], 0.f);
    hout[(long)wid * HID_F + lane] = acc0;
    if (lo) {
        acc1 = fmaxf(acc1 + ds * rown[64 + lane] + bias[64 + lane], 0.f);
        hout[(long)wid * HID_F + 64 + lane] = acc1;
    }
}

// ---------- prop (layer 2) fused with z = relu(agg+b2) . wv : writes scalar z[node] ----------

__global__ __launch_bounds__(256) void prop_dot_kernel(
        const float* __restrict__ hin, const int* __restrict__ rowoff,
        const int2* __restrict__ ecw,
        const float* __restrict__ dinv, const float* __restrict__ bias,
        const float* __restrict__ wv, float* __restrict__ z, int n) {
    int wid = (blockIdx.x * blockDim.x + threadIdx.x) >> 6;
    int lane = threadIdx.x & 63;
    if (wid >= n) return;
    int e0 = rowoff[wid], e1 = rowoff[wid + 1];
    float acc0 = 0.f, acc1 = 0.f;
    bool lo = lane < 32;
    int e = e0;
    for (; e + 4 <= e1; e += 4) {
        int2 c0 = ecw[e + 0], c1 = ecw[e + 1], c2 = ecw[e + 2], c3 = ecw[e + 3];
        const float* r0 = hin + (long)c0.x * HID_F;
        const float* r1 = hin + (long)c1.x * HID_F;
        const float* r2 = hin + (long)c2.x * HID_F;
        const float* r3 = hin + (long)c3.x * HID_F;
        float a0 = r0[lane], a1 = r1[lane], a2 = r2[lane], a3 = r3[lane];
        float b0 = 0.f, b1 = 0.f, b2 = 0.f, b3 = 0.f;
        if (lo) { b0 = r0[64 + lane]; b1 = r1[64 + lane]; b2 = r2[64 + lane]; b3 = r3[64 + lane]; }
        float w0 = __int_as_float(c0.y), w1 = __int_as_float(c1.y);
        float w2 = __int_as_float(c2.y), w3 = __int_as_float(c3.y);
        acc0 += w0 * a0; acc0 += w1 * a1; acc0 += w2 * a2; acc0 += w3 * a3;
        acc1 += w0 * b0; acc1 += w1 * b1; acc1 += w2 * b2; acc1 += w3 * b3;
    }
    for (; e < e1; ++e) {
        int2 c = ecw[e];
        const float* row = hin + (long)c.x * HID_F;
        float ww = __int_as_float(c.y);
        acc0 += ww * row[lane];
        if (lo) acc1 += ww * row[64 + lane];
    }
    float ds = dinv[wid]; ds *= ds;
    const float* rown = hin + (long)wid * HID_F;
    acc0 = fmaxf(acc0 + ds * rown[lane] + bias[lane], 0.f);
    float v = acc0 * wv[lane];
    if (lo) {
        acc1 = fmaxf(acc1 + ds * rown[64 + lane] + bias[64 + lane], 0.f);
        v += acc1 * wv[64 + lane];
    }
#pragma unroll
    for (int off = 32; off; off >>= 1) v += __shfl_xor(v, off, 64);
    if (lane == 0) z[wid] = v;
}

// ---------- layer-3 prop over scalar z: out[d] = sum w[e]*z[col] + dinv2*z[d] + c ----------

__global__ __launch_bounds__(256) void prop_scalar_kernel(
        const float* __restrict__ z, const int* __restrict__ rowoff,
        const int2* __restrict__ ecw,
        const float* __restrict__ dinv, const float* __restrict__ cconst,
        float* __restrict__ out, int n) {
    int i = blockIdx.x * blockDim.x + threadIdx.x;
    if (i >= n) return;
    int e0 = rowoff[i], e1 = rowoff[i + 1];
    float s = 0.f;
    int e = e0;
    for (; e + 4 <= e1; e += 4) {
        int2 c0 = ecw[e + 0], c1 = ecw[e + 1], c2 = ecw[e + 2], c3 = ecw[e + 3];
        float z0 = z[c0.x], z1 = z[c1.x], z2 = z[c2.x], z3 = z[c3.x];
        s += __int_as_float(c0.y) * z0; s += __int_as_float(c1.y) * z1;
        s += __int_as_float(c2.y) * z2; s += __int_as_float(c3.y) * z3;
    }
    for (; e < e1; ++e) {
        int2 c = ecw[e];
        s += __int_as_float(c.y) * z[c.x];
    }
    float ds = dinv[i]; ds *= ds;
    out[i] = s + ds * z[i] + cconst[0];
}

// ---------- launch ----------

extern "C" void kernel_launch(void* const* d_in, const int* in_sizes, int n_in,
                              void* d_out, int out_size, void* d_ws, size_t ws_size,
                              hipStream_t stream) {
    const float* x    = (const float*)d_in[0];
    const int*   eidx = (const int*)d_in[1];
    const float* mean = (const float*)d_in[3];
    const float* stdv = (const float*)d_in[4];
    const float* W1   = (const float*)d_in[5];
    const float* b1   = (const float*)d_in[6];
    const float* W2   = (const float*)d_in[7];
    const float* b2   = (const float*)d_in[8];
    const float* W3   = (const float*)d_in[9];
    const float* b3   = (const float*)d_in[10];
    const float* Wout = (const float*)d_in[11];
    const float* bout = (const float*)d_in[12];
    float* out = (float*)d_out;

    const int n = in_sizes[0] / IN_F;       // 50000
    const int E = in_sizes[1] / 2;          // 800000
    const int* srcv = eidx;
    const int* dstv = eidx + E;

    char* ws = (char*)d_ws;
    size_t off = 0;
    auto alloc = [&](size_t bytes) -> void* {
        void* p = ws + off;
        off = (off + bytes + 255) & ~(size_t)255;
        return p;
    };
    int*   deg    = (int*)alloc((size_t)n * 4);
    int*   fill   = (int*)alloc((size_t)n * 4);
    int*   rowoff = (int*)alloc(((size_t)n + 1) * 4);
    float* dinv   = (float*)alloc((size_t)n * 4);
    int2*  ecw    = (int2*)alloc((size_t)E * 8);
    float* rstd   = (float*)alloc(IN_F * 4);
    float* wv     = (float*)alloc(HID_F * 4);
    float* cconst = (float*)alloc(4);
    float* zbuf   = (float*)alloc((size_t)n * 4);
    float* bufA   = (float*)alloc((size_t)n * HID_F * 4);
    float* bufB   = (float*)alloc((size_t)n * HID_F * 4);

    hipMemsetAsync(deg, 0, (size_t)n * 4, stream);
    hipMemsetAsync(fill, 0, (size_t)n * 4, stream);

    prep_kernel<<<1, 128, 0, stream>>>(stdv, rstd, W3, Wout, b3, bout, wv, cconst);
    count_kernel<<<(E + 255) / 256, 256, 0, stream>>>(dstv, deg, E);
    dinv_kernel<<<(n + 255) / 256, 256, 0, stream>>>(deg, dinv, n);
    scan_kernel<<<1, 256, 0, stream>>>(deg, rowoff, n, E);
    scatter_kernel<<<(E + 255) / 256, 256, 0, stream>>>(srcv, dstv, rowoff, fill, dinv,
                                                        ecw, E);

    int gemm_grid = (n + 63) / 64;
    int prop_grid = (int)(((long)n * 64 + 255) / 256);

    // layer 1: GEMM (fused standardization) -> prop+b1+relu
    gemm_kernel<<<gemm_grid, 256, 0, stream>>>(x, W1, mean, rstd, bufA, n, IN_F, 1);
    prop_kernel<<<prop_grid, 256, 0, stream>>>(bufA, rowoff, ecw, dinv, b1, bufB, n);
    // layer 2: GEMM -> prop+b2+relu fused with dot(wv) -> scalar z
    gemm_kernel<<<gemm_grid, 256, 0, stream>>>(bufB, W2, nullptr, nullptr, bufA, n, HID_F, 0);
    prop_dot_kernel<<<prop_grid, 256, 0, stream>>>(bufA, rowoff, ecw, dinv, b2, wv, zbuf, n);
    // layer 3 (folded): scalar prop over z
    prop_scalar_kernel<<<(n + 255) / 256, 256, 0, stream>>>(zbuf, rowoff, ecw, dinv,
                                                            cconst, out, n);
}

// Round 4
// 342.297 us; speedup vs baseline: 1.7770x; 1.2191x over previous
//
#include <hip/hip_runtime.h>

#define IN_F 128
#define HID_F 96

// ---------- small prep: rstd, folded wv = W3 @ Wout[:,1], c = b3.Wout[:,1] + bout[1] ----------

__global__ void prep_kernel(const float* __restrict__ stdv, float* __restrict__ rstd,
                            const float* __restrict__ W3, const float* __restrict__ Wout,
                            const float* __restrict__ b3, const float* __restrict__ bout,
                            float* __restrict__ wv, float* __restrict__ cconst) {
    int t = threadIdx.x;
    if (t < IN_F) rstd[t] = 1.0f / stdv[t];
    if (t < HID_F) {
        float s = 0.f;
        for (int j = 0; j < HID_F; ++j) s += W3[t * HID_F + j] * Wout[j * 2 + 1];
        wv[t] = s;
    }
    if (t == 0) {
        float s = 0.f;
        for (int j = 0; j < HID_F; ++j) s += b3[j] * Wout[j * 2 + 1];
        cconst[0] = s + bout[1];
    }
}

// ---------- CSR build ----------

__global__ void count_kernel(const int* __restrict__ dst, int* __restrict__ deg, int E) {
    int i = blockIdx.x * blockDim.x + threadIdx.x;
    if (i < E) atomicAdd(&deg[dst[i]], 1);
}

__global__ void dinv_kernel(const int* __restrict__ deg, float* __restrict__ dinv, int n) {
    int i = blockIdx.x * blockDim.x + threadIdx.x;
    if (i < n) dinv[i] = rsqrtf((float)deg[i] + 1.0f);  // +1 self-loop
}

// ---------- device-wide exclusive scan of deg -> rowoff, 3 phases ----------
// phase 1: per-block Hillis-Steele scan, write exclusive partials + block sums
__global__ __launch_bounds__(256) void scan_p1_kernel(
        const int* __restrict__ cnt, int* __restrict__ rowoff,
        int* __restrict__ bsum, int n) {
    __shared__ int tmp[256];
    int t = threadIdx.x;
    int i = blockIdx.x * 256 + t;
    int v = (i < n) ? cnt[i] : 0;
    tmp[t] = v;
    __syncthreads();
#pragma unroll
    for (int off = 1; off < 256; off <<= 1) {
        int u = (t >= off) ? tmp[t - off] : 0;
        __syncthreads();
        tmp[t] += u;
        __syncthreads();
    }
    if (i < n) rowoff[i] = tmp[t] - v;  // exclusive within block
    if (t == 255) bsum[blockIdx.x] = tmp[255];
}

// phase 2: single-block exclusive scan of block sums (nb <= 1024)
__global__ __launch_bounds__(1024) void scan_p2_kernel(int* __restrict__ bsum, int nb) {
    __shared__ int tmp[1024];
    int t = threadIdx.x;
    int v = (t < nb) ? bsum[t] : 0;
    tmp[t] = v;
    __syncthreads();
#pragma unroll
    for (int off = 1; off < 1024; off <<= 1) {
        int u = (t >= off) ? tmp[t - off] : 0;
        __syncthreads();
        tmp[t] += u;
        __syncthreads();
    }
    if (t < nb) bsum[t] = tmp[t] - v;  // exclusive
}

// phase 3: add block offsets, set rowoff[n]
__global__ __launch_bounds__(256) void scan_p3_kernel(
        int* __restrict__ rowoff, const int* __restrict__ bsum, int n, int total) {
    int i = blockIdx.x * 256 + threadIdx.x;
    if (i < n) rowoff[i] += bsum[blockIdx.x];
    if (i == 0) rowoff[n] = total;
}

// packed edge record: .x = src node, .y = float bits of norm weight
__global__ void scatter_kernel(const int* __restrict__ srcv, const int* __restrict__ dstv,
                               const int* __restrict__ rowoff, int* __restrict__ fill,
                               const float* __restrict__ dinv,
                               int2* __restrict__ ecw, int E) {
    int i = blockIdx.x * blockDim.x + threadIdx.x;
    if (i < E) {
        int s = srcv[i], d = dstv[i];
        int pos = rowoff[d] + atomicAdd(&fill[d], 1);
        int2 r;
        r.x = s;
        r.y = __float_as_int(dinv[s] * dinv[d]);
        ecw[pos] = r;
    }
}

// ---------- fp32 GEMM: C[N,96] = A[N,K] @ W[K,96], optional input standardization ----------

__global__ __launch_bounds__(256) void gemm_kernel(
        const float* __restrict__ A, const float* __restrict__ W,
        const float* __restrict__ mean, const float* __restrict__ rstd,
        float* __restrict__ C, int n, int K, int norm) {
    __shared__ float As[64][33];
    __shared__ float Ws[32][96];
    int tid = threadIdx.x;
    int ti = tid >> 4;
    int tj = tid & 15;
    int node0 = blockIdx.x * 64;

    float acc[4][6];
#pragma unroll
    for (int i = 0; i < 4; ++i)
#pragma unroll
        for (int m = 0; m < 6; ++m) acc[i][m] = 0.f;

    for (int k0 = 0; k0 < K; k0 += 32) {
#pragma unroll
        for (int L = 0; L < 2; ++L) {
            int idx = tid + L * 256;
            int r = idx >> 3, q = idx & 7;
            int g = node0 + r;
            float4 v = make_float4(0.f, 0.f, 0.f, 0.f);
            if (g < n) v = *(const float4*)(A + (long)g * K + k0 + q * 4);
            if (norm) {
                float4 mu = *(const float4*)(mean + k0 + q * 4);
                float4 rs = *(const float4*)(rstd + k0 + q * 4);
                v.x = (v.x - mu.x) * rs.x; v.y = (v.y - mu.y) * rs.y;
                v.z = (v.z - mu.z) * rs.z; v.w = (v.w - mu.w) * rs.w;
            }
            As[r][q * 4 + 0] = v.x; As[r][q * 4 + 1] = v.y;
            As[r][q * 4 + 2] = v.z; As[r][q * 4 + 3] = v.w;
        }
#pragma unroll
        for (int L = 0; L < 3; ++L) {
            int idx = tid + L * 256;
            int kr = idx / 24, jq = idx % 24;
            float4 v = *(const float4*)(W + (long)(k0 + kr) * 96 + jq * 4);
            Ws[kr][jq * 4 + 0] = v.x; Ws[kr][jq * 4 + 1] = v.y;
            Ws[kr][jq * 4 + 2] = v.z; Ws[kr][jq * 4 + 3] = v.w;
        }
        __syncthreads();
#pragma unroll
        for (int kk = 0; kk < 32; ++kk) {
            float av[4];
            av[0] = As[ti][kk]; av[1] = As[ti + 16][kk];
            av[2] = As[ti + 32][kk]; av[3] = As[ti + 48][kk];
            const float2* wr = (const float2*)&Ws[kk][0];
            float2 w01 = wr[tj * 3 + 0];
            float2 w23 = wr[tj * 3 + 1];
            float2 w45 = wr[tj * 3 + 2];
            float wv6[6] = { w01.x, w01.y, w23.x, w23.y, w45.x, w45.y };
#pragma unroll
            for (int i = 0; i < 4; ++i)
#pragma unroll
                for (int m = 0; m < 6; ++m) acc[i][m] += av[i] * wv6[m];
        }
        __syncthreads();
    }
#pragma unroll
    for (int i = 0; i < 4; ++i) {
        int g = node0 + ti + 16 * i;
        if (g < n) {
            float* crow = C + (long)g * 96 + tj * 6;
#pragma unroll
            for (int m = 0; m < 6; ++m) crow[m] = acc[i][m];
        }
    }
}

// ---------- pull-based prop (layer 1): wave per node, lane = channel, edge loop x4 ----------

__global__ __launch_bounds__(256) void prop_kernel(
        const float* __restrict__ hin, const int* __restrict__ rowoff,
        const int2* __restrict__ ecw,
        const float* __restrict__ dinv, const float* __restrict__ bias,
        float* __restrict__ hout, int n) {
    int wid = (blockIdx.x * blockDim.x + threadIdx.x) >> 6;
    int lane = threadIdx.x & 63;
    if (wid >= n) return;
    int e0 = rowoff[wid], e1 = rowoff[wid + 1];
    float acc0 = 0.f, acc1 = 0.f;
    bool lo = lane < 32;
    int e = e0;
    for (; e + 4 <= e1; e += 4) {
        int2 c0 = ecw[e + 0], c1 = ecw[e + 1], c2 = ecw[e + 2], c3 = ecw[e + 3];
        const float* r0 = hin + (long)c0.x * HID_F;
        const float* r1 = hin + (long)c1.x * HID_F;
        const float* r2 = hin + (long)c2.x * HID_F;
        const float* r3 = hin + (long)c3.x * HID_F;
        float a0 = r0[lane], a1 = r1[lane], a2 = r2[lane], a3 = r3[lane];
        float b0 = 0.f, b1 = 0.f, b2 = 0.f, b3 = 0.f;
        if (lo) { b0 = r0[64 + lane]; b1 = r1[64 + lane]; b2 = r2[64 + lane]; b3 = r3[64 + lane]; }
        float w0 = __int_as_float(c0.y), w1 = __int_as_float(c1.y);
        float w2 = __int_as_float(c2.y), w3 = __int_as_float(c3.y);
        acc0 += w0 * a0; acc0 += w1 * a1; acc0 += w2 * a2; acc0 += w3 * a3;
        acc1 += w0 * b0; acc1 += w1 * b1; acc1 += w2 * b2; acc1 += w3 * b3;
    }
    for (; e < e1; ++e) {
        int2 c = ecw[e];
        const float* row = hin + (long)c.x * HID_F;
        float ww = __int_as_float(c.y);
        acc0 += ww * row[lane];
        if (lo) acc1 += ww * row[64 + lane];
    }
    float ds = dinv[wid]; ds *= ds;
    const float* rown = hin + (long)wid * HID_F;
    acc0 = fmaxf(acc0 + ds * rown[lane] + bias[lane], 0.f);
    hout[(long)wid * HID_F + lane] = acc0;
    if (lo) {
        acc1 = fmaxf(acc1 + ds * rown[64 + lane] + bias[64 + lane], 0.f);
        hout[(long)wid * HID_F + 64 + lane] = acc1;
    }
}

// ---------- prop (layer 2) fused with z = relu(agg+b2) . wv : writes scalar z[node] ----------

__global__ __launch_bounds__(256) void prop_dot_kernel(
        const float* __restrict__ hin, const int* __restrict__ rowoff,
        const int2* __restrict__ ecw,
        const float* __restrict__ dinv, const float* __restrict__ bias,
        const float* __restrict__ wv, float* __restrict__ z, int n) {
    int wid = (blockIdx.x * blockDim.x + threadIdx.x) >> 6;
    int lane = threadIdx.x & 63;
    if (wid >= n) return;
    int e0 = rowoff[wid], e1 = rowoff[wid + 1];
    float acc0 = 0.f, acc1 = 0.f;
    bool lo = lane < 32;
    int e = e0;
    for (; e + 4 <= e1; e += 4) {
        int2 c0 = ecw[e + 0], c1 = ecw[e + 1], c2 = ecw[e + 2], c3 = ecw[e + 3];
        const float* r0 = hin + (long)c0.x * HID_F;
        const float* r1 = hin + (long)c1.x * HID_F;
        const float* r2 = hin + (long)c2.x * HID_F;
        const float* r3 = hin + (long)c3.x * HID_F;
        float a0 = r0[lane], a1 = r1[lane], a2 = r2[lane], a3 = r3[lane];
        float b0 = 0.f, b1 = 0.f, b2 = 0.f, b3 = 0.f;
        if (lo) { b0 = r0[64 + lane]; b1 = r1[64 + lane]; b2 = r2[64 + lane]; b3 = r3[64 + lane]; }
        float w0 = __int_as_float(c0.y), w1 = __int_as_float(c1.y);
        float w2 = __int_as_float(c2.y), w3 = __int_as_float(c3.y);
        acc0 += w0 * a0; acc0 += w1 * a1; acc0 += w2 * a2; acc0 += w3 * a3;
        acc1 += w0 * b0; acc1 += w1 * b1; acc1 += w2 * b2; acc1 += w3 * b3;
    }
    for (; e < e1; ++e) {
        int2 c = ecw[e];
        const float* row = hin + (long)c.x * HID_F;
        float ww = __int_as_float(c.y);
        acc0 += ww * row[lane];
        if (lo) acc1 += ww * row[64 + lane];
    }
    float ds = dinv[wid]; ds *= ds;
    const float* rown = hin + (long)wid * HID_F;
    acc0 = fmaxf(acc0 + ds * rown[lane] + bias[lane], 0.f);
    float v = acc0 * wv[lane];
    if (lo) {
        acc1 = fmaxf(acc1 + ds * rown[64 + lane] + bias[64 + lane], 0.f);
        v += acc1 * wv[64 + lane];
    }
#pragma unroll
    for (int off = 32; off; off >>= 1) v += __shfl_xor(v, off, 64);
    if (lane == 0) z[wid] = v;
}

// ---------- layer-3 prop over scalar z: out[d] = sum w[e]*z[col] + dinv2*z[d] + c ----------

__global__ __launch_bounds__(256) void prop_scalar_kernel(
        const float* __restrict__ z, const int* __restrict__ rowoff,
        const int2* __restrict__ ecw,
        const float* __restrict__ dinv, const float* __restrict__ cconst,
        float* __restrict__ out, int n) {
    int i = blockIdx.x * blockDim.x + threadIdx.x;
    if (i >= n) return;
    int e0 = rowoff[i], e1 = rowoff[i + 1];
    float s = 0.f;
    int e = e0;
    for (; e + 4 <= e1; e += 4) {
        int2 c0 = ecw[e + 0], c1 = ecw[e + 1], c2 = ecw[e + 2], c3 = ecw[e + 3];
        float z0 = z[c0.x], z1 = z[c1.x], z2 = z[c2.x], z3 = z[c3.x];
        s += __int_as_float(c0.y) * z0; s += __int_as_float(c1.y) * z1;
        s += __int_as_float(c2.y) * z2; s += __int_as_float(c3.y) * z3;
    }
    for (; e < e1; ++e) {
        int2 c = ecw[e];
        s += __int_as_float(c.y) * z[c.x];
    }
    float ds = dinv[i]; ds *= ds;
    out[i] = s + ds * z[i] + cconst[0];
}

// ---------- launch ----------

extern "C" void kernel_launch(void* const* d_in, const int* in_sizes, int n_in,
                              void* d_out, int out_size, void* d_ws, size_t ws_size,
                              hipStream_t stream) {
    const float* x    = (const float*)d_in[0];
    const int*   eidx = (const int*)d_in[1];
    const float* mean = (const float*)d_in[3];
    const float* stdv = (const float*)d_in[4];
    const float* W1   = (const float*)d_in[5];
    const float* b1   = (const float*)d_in[6];
    const float* W2   = (const float*)d_in[7];
    const float* b2   = (const float*)d_in[8];
    const float* W3   = (const float*)d_in[9];
    const float* b3   = (const float*)d_in[10];
    const float* Wout = (const float*)d_in[11];
    const float* bout = (const float*)d_in[12];
    float* out = (float*)d_out;

    const int n = in_sizes[0] / IN_F;       // 50000
    const int E = in_sizes[1] / 2;          // 800000
    const int* srcv = eidx;
    const int* dstv = eidx + E;

    char* ws = (char*)d_ws;
    size_t off = 0;
    auto alloc = [&](size_t bytes) -> void* {
        void* p = ws + off;
        off = (off + bytes + 255) & ~(size_t)255;
        return p;
    };
    int nscanb = (n + 255) / 256;           // 196 blocks
    int*   deg    = (int*)alloc((size_t)n * 4);
    int*   fill   = (int*)alloc((size_t)n * 4);
    int*   rowoff = (int*)alloc(((size_t)n + 1) * 4);
    int*   bsum   = (int*)alloc((size_t)nscanb * 4);
    float* dinv   = (float*)alloc((size_t)n * 4);
    int2*  ecw    = (int2*)alloc((size_t)E * 8);
    float* rstd   = (float*)alloc(IN_F * 4);
    float* wv     = (float*)alloc(HID_F * 4);
    float* cconst = (float*)alloc(4);
    float* zbuf   = (float*)alloc((size_t)n * 4);
    float* bufA   = (float*)alloc((size_t)n * HID_F * 4);
    float* bufB   = (float*)alloc((size_t)n * HID_F * 4);

    hipMemsetAsync(deg, 0, (size_t)n * 4, stream);
    hipMemsetAsync(fill, 0, (size_t)n * 4, stream);

    prep_kernel<<<1, 128, 0, stream>>>(stdv, rstd, W3, Wout, b3, bout, wv, cconst);
    count_kernel<<<(E + 255) / 256, 256, 0, stream>>>(dstv, deg, E);
    dinv_kernel<<<(n + 255) / 256, 256, 0, stream>>>(deg, dinv, n);
    scan_p1_kernel<<<nscanb, 256, 0, stream>>>(deg, rowoff, bsum, n);
    scan_p2_kernel<<<1, 1024, 0, stream>>>(bsum, nscanb);
    scan_p3_kernel<<<nscanb, 256, 0, stream>>>(rowoff, bsum, n, E);
    scatter_kernel<<<(E + 255) / 256, 256, 0, stream>>>(srcv, dstv, rowoff, fill, dinv,
                                                        ecw, E);

    int gemm_grid = (n + 63) / 64;
    int prop_grid = (int)(((long)n * 64 + 255) / 256);

    // layer 1: GEMM (fused standardization) -> prop+b1+relu
    gemm_kernel<<<gemm_grid, 256, 0, stream>>>(x, W1, mean, rstd, bufA, n, IN_F, 1);
    prop_kernel<<<prop_grid, 256, 0, stream>>>(bufA, rowoff, ecw, dinv, b1, bufB, n);
    // layer 2: GEMM -> prop+b2+relu fused with dot(wv) -> scalar z
    gemm_kernel<<<gemm_grid, 256, 0, stream>>>(bufB, W2, nullptr, nullptr, bufA, n, HID_F, 0);
    prop_dot_kernel<<<prop_grid, 256, 0, stream>>>(bufA, rowoff, ecw, dinv, b2, wv, zbuf, n);
    // layer 3 (folded): scalar prop over z
    prop_scalar_kernel<<<(n + 255) / 256, 256, 0, stream>>>(zbuf, rowoff, ecw, dinv,
                                                            cconst, out, n);
}

// Round 5
// 326.246 us; speedup vs baseline: 1.8644x; 1.0492x over previous
//
#include <hip/hip_runtime.h>
#include <hip/hip_fp16.h>

#define IN_F 128
#define HID_F 96

// ---------- small prep: rstd, folded wv = W3 @ Wout[:,1], c = b3.Wout[:,1] + bout[1] ----------

__global__ void prep_kernel(const float* __restrict__ stdv, float* __restrict__ rstd,
                            const float* __restrict__ W3, const float* __restrict__ Wout,
                            const float* __restrict__ b3, const float* __restrict__ bout,
                            float* __restrict__ wv, float* __restrict__ cconst) {
    int t = threadIdx.x;
    if (t < IN_F) rstd[t] = 1.0f / stdv[t];
    if (t < HID_F) {
        float s = 0.f;
        for (int j = 0; j < HID_F; ++j) s += W3[t * HID_F + j] * Wout[j * 2 + 1];
        wv[t] = s;
    }
    if (t == 0) {
        float s = 0.f;
        for (int j = 0; j < HID_F; ++j) s += b3[j] * Wout[j * 2 + 1];
        cconst[0] = s + bout[1];
    }
}

// ---------- CSR build ----------

__global__ void count_kernel(const int* __restrict__ dst, int* __restrict__ deg, int E) {
    int i = blockIdx.x * blockDim.x + threadIdx.x;
    if (i < E) atomicAdd(&deg[dst[i]], 1);
}

__global__ void dinv_kernel(const int* __restrict__ deg, float* __restrict__ dinv, int n) {
    int i = blockIdx.x * blockDim.x + threadIdx.x;
    if (i < n) dinv[i] = rsqrtf((float)deg[i] + 1.0f);  // +1 self-loop
}

// ---------- device-wide exclusive scan of deg -> rowoff, 3 phases ----------
__global__ __launch_bounds__(256) void scan_p1_kernel(
        const int* __restrict__ cnt, int* __restrict__ rowoff,
        int* __restrict__ bsum, int n) {
    __shared__ int tmp[256];
    int t = threadIdx.x;
    int i = blockIdx.x * 256 + t;
    int v = (i < n) ? cnt[i] : 0;
    tmp[t] = v;
    __syncthreads();
#pragma unroll
    for (int off = 1; off < 256; off <<= 1) {
        int u = (t >= off) ? tmp[t - off] : 0;
        __syncthreads();
        tmp[t] += u;
        __syncthreads();
    }
    if (i < n) rowoff[i] = tmp[t] - v;
    if (t == 255) bsum[blockIdx.x] = tmp[255];
}

__global__ __launch_bounds__(1024) void scan_p2_kernel(int* __restrict__ bsum, int nb) {
    __shared__ int tmp[1024];
    int t = threadIdx.x;
    int v = (t < nb) ? bsum[t] : 0;
    tmp[t] = v;
    __syncthreads();
#pragma unroll
    for (int off = 1; off < 1024; off <<= 1) {
        int u = (t >= off) ? tmp[t - off] : 0;
        __syncthreads();
        tmp[t] += u;
        __syncthreads();
    }
    if (t < nb) bsum[t] = tmp[t] - v;
}

__global__ __launch_bounds__(256) void scan_p3_kernel(
        int* __restrict__ rowoff, const int* __restrict__ bsum, int n, int total) {
    int i = blockIdx.x * 256 + threadIdx.x;
    if (i < n) rowoff[i] += bsum[blockIdx.x];
    if (i == 0) rowoff[n] = total;
}

// packed edge record: .x = src node, .y = float bits of norm weight
__global__ void scatter_kernel(const int* __restrict__ srcv, const int* __restrict__ dstv,
                               const int* __restrict__ rowoff, int* __restrict__ fill,
                               const float* __restrict__ dinv,
                               int2* __restrict__ ecw, int E) {
    int i = blockIdx.x * blockDim.x + threadIdx.x;
    if (i < E) {
        int s = srcv[i], d = dstv[i];
        int pos = rowoff[d] + atomicAdd(&fill[d], 1);
        int2 r;
        r.x = s;
        r.y = __float_as_int(dinv[s] * dinv[d]);
        ecw[pos] = r;
    }
}

// ---------- fp32 GEMM: C[N,96](fp16) = A[N,K](fp32) @ W[K,96], optional standardization ----
// C is stored as __half rows (192 B/row) -- it is only consumed by the gather props.

__global__ __launch_bounds__(256) void gemm_kernel(
        const float* __restrict__ A, const float* __restrict__ W,
        const float* __restrict__ mean, const float* __restrict__ rstd,
        __half* __restrict__ C, int n, int K, int norm) {
    __shared__ float As[64][33];
    __shared__ float Ws[32][96];
    int tid = threadIdx.x;
    int ti = tid >> 4;
    int tj = tid & 15;
    int node0 = blockIdx.x * 64;

    float acc[4][6];
#pragma unroll
    for (int i = 0; i < 4; ++i)
#pragma unroll
        for (int m = 0; m < 6; ++m) acc[i][m] = 0.f;

    for (int k0 = 0; k0 < K; k0 += 32) {
#pragma unroll
        for (int L = 0; L < 2; ++L) {
            int idx = tid + L * 256;
            int r = idx >> 3, q = idx & 7;
            int g = node0 + r;
            float4 v = make_float4(0.f, 0.f, 0.f, 0.f);
            if (g < n) v = *(const float4*)(A + (long)g * K + k0 + q * 4);
            if (norm) {
                float4 mu = *(const float4*)(mean + k0 + q * 4);
                float4 rs = *(const float4*)(rstd + k0 + q * 4);
                v.x = (v.x - mu.x) * rs.x; v.y = (v.y - mu.y) * rs.y;
                v.z = (v.z - mu.z) * rs.z; v.w = (v.w - mu.w) * rs.w;
            }
            As[r][q * 4 + 0] = v.x; As[r][q * 4 + 1] = v.y;
            As[r][q * 4 + 2] = v.z; As[r][q * 4 + 3] = v.w;
        }
#pragma unroll
        for (int L = 0; L < 3; ++L) {
            int idx = tid + L * 256;
            int kr = idx / 24, jq = idx % 24;
            float4 v = *(const float4*)(W + (long)(k0 + kr) * 96 + jq * 4);
            Ws[kr][jq * 4 + 0] = v.x; Ws[kr][jq * 4 + 1] = v.y;
            Ws[kr][jq * 4 + 2] = v.z; Ws[kr][jq * 4 + 3] = v.w;
        }
        __syncthreads();
#pragma unroll
        for (int kk = 0; kk < 32; ++kk) {
            float av[4];
            av[0] = As[ti][kk]; av[1] = As[ti + 16][kk];
            av[2] = As[ti + 32][kk]; av[3] = As[ti + 48][kk];
            const float2* wr = (const float2*)&Ws[kk][0];
            float2 w01 = wr[tj * 3 + 0];
            float2 w23 = wr[tj * 3 + 1];
            float2 w45 = wr[tj * 3 + 2];
            float wv6[6] = { w01.x, w01.y, w23.x, w23.y, w45.x, w45.y };
#pragma unroll
            for (int i = 0; i < 4; ++i)
#pragma unroll
                for (int m = 0; m < 6; ++m) acc[i][m] += av[i] * wv6[m];
        }
        __syncthreads();
    }
#pragma unroll
    for (int i = 0; i < 4; ++i) {
        int g = node0 + ti + 16 * i;
        if (g < n) {
            __half2* crow = (__half2*)(C + (long)g * 96) + tj * 3;
            crow[0] = __floats2half2_rn(acc[i][0], acc[i][1]);
            crow[1] = __floats2half2_rn(acc[i][2], acc[i][3]);
            crow[2] = __floats2half2_rn(acc[i][4], acc[i][5]);
        }
    }
}

// ---------- pull-based prop (layer 1): wave per node, lane<48 holds half2 channel pair ----
// hin: fp16 rows [n][96]; hout: fp32 rows [n][96]

__global__ __launch_bounds__(256) void prop_kernel(
        const __half2* __restrict__ hin, const int* __restrict__ rowoff,
        const int2* __restrict__ ecw,
        const float* __restrict__ dinv, const float* __restrict__ bias,
        float* __restrict__ hout, int n) {
    int wid = (blockIdx.x * blockDim.x + threadIdx.x) >> 6;
    int lane = threadIdx.x & 63;
    if (wid >= n) return;
    int e0 = rowoff[wid], e1 = rowoff[wid + 1];
    bool act = lane < 48;
    int li = act ? lane : 0;
    float ax = 0.f, ay = 0.f;
    int e = e0;
    for (; e + 8 <= e1; e += 8) {
        int2 c[8];
        __half2 g[8];
#pragma unroll
        for (int k = 0; k < 8; ++k) c[k] = ecw[e + k];
#pragma unroll
        for (int k = 0; k < 8; ++k) g[k] = hin[(long)c[k].x * 48 + li];
#pragma unroll
        for (int k = 0; k < 8; ++k) {
            float w = __int_as_float(c[k].y);
            float2 f = __half22float2(g[k]);
            ax += w * f.x; ay += w * f.y;
        }
    }
    for (; e < e1; ++e) {
        int2 c = ecw[e];
        float w = __int_as_float(c.y);
        float2 f = __half22float2(hin[(long)c.x * 48 + li]);
        ax += w * f.x; ay += w * f.y;
    }
    float ds = dinv[wid]; ds *= ds;
    float2 self = __half22float2(hin[(long)wid * 48 + li]);
    ax += ds * self.x; ay += ds * self.y;
    if (act) {
        float2 b = ((const float2*)bias)[li];
        float2 o;
        o.x = fmaxf(ax + b.x, 0.f);
        o.y = fmaxf(ay + b.y, 0.f);
        ((float2*)(hout + (long)wid * HID_F))[li] = o;
    }
}

// ---------- prop (layer 2) fused with z = relu(agg+b2) . wv : writes scalar z[node] ------

__global__ __launch_bounds__(256) void prop_dot_kernel(
        const __half2* __restrict__ hin, const int* __restrict__ rowoff,
        const int2* __restrict__ ecw,
        const float* __restrict__ dinv, const float* __restrict__ bias,
        const float* __restrict__ wv, float* __restrict__ z, int n) {
    int wid = (blockIdx.x * blockDim.x + threadIdx.x) >> 6;
    int lane = threadIdx.x & 63;
    if (wid >= n) return;
    int e0 = rowoff[wid], e1 = rowoff[wid + 1];
    bool act = lane < 48;
    int li = act ? lane : 0;
    float ax = 0.f, ay = 0.f;
    int e = e0;
    for (; e + 8 <= e1; e += 8) {
        int2 c[8];
        __half2 g[8];
#pragma unroll
        for (int k = 0; k < 8; ++k) c[k] = ecw[e + k];
#pragma unroll
        for (int k = 0; k < 8; ++k) g[k] = hin[(long)c[k].x * 48 + li];
#pragma unroll
        for (int k = 0; k < 8; ++k) {
            float w = __int_as_float(c[k].y);
            float2 f = __half22float2(g[k]);
            ax += w * f.x; ay += w * f.y;
        }
    }
    for (; e < e1; ++e) {
        int2 c = ecw[e];
        float w = __int_as_float(c.y);
        float2 f = __half22float2(hin[(long)c.x * 48 + li]);
        ax += w * f.x; ay += w * f.y;
    }
    float ds = dinv[wid]; ds *= ds;
    float2 self = __half22float2(hin[(long)wid * 48 + li]);
    ax += ds * self.x; ay += ds * self.y;
    float v = 0.f;
    if (act) {
        float2 b = ((const float2*)bias)[li];
        float2 wp = ((const float2*)wv)[li];
        v = fmaxf(ax + b.x, 0.f) * wp.x + fmaxf(ay + b.y, 0.f) * wp.y;
    }
#pragma unroll
    for (int off = 32; off; off >>= 1) v += __shfl_xor(v, off, 64);
    if (lane == 0) z[wid] = v;
}

// ---------- layer-3 prop over scalar z: out[d] = sum w[e]*z[col] + dinv2*z[d] + c ----------

__global__ __launch_bounds__(256) void prop_scalar_kernel(
        const float* __restrict__ z, const int* __restrict__ rowoff,
        const int2* __restrict__ ecw,
        const float* __restrict__ dinv, const float* __restrict__ cconst,
        float* __restrict__ out, int n) {
    int i = blockIdx.x * blockDim.x + threadIdx.x;
    if (i >= n) return;
    int e0 = rowoff[i], e1 = rowoff[i + 1];
    float s = 0.f;
    int e = e0;
    for (; e + 4 <= e1; e += 4) {
        int2 c0 = ecw[e + 0], c1 = ecw[e + 1], c2 = ecw[e + 2], c3 = ecw[e + 3];
        float z0 = z[c0.x], z1 = z[c1.x], z2 = z[c2.x], z3 = z[c3.x];
        s += __int_as_float(c0.y) * z0; s += __int_as_float(c1.y) * z1;
        s += __int_as_float(c2.y) * z2; s += __int_as_float(c3.y) * z3;
    }
    for (; e < e1; ++e) {
        int2 c = ecw[e];
        s += __int_as_float(c.y) * z[c.x];
    }
    float ds = dinv[i]; ds *= ds;
    out[i] = s + ds * z[i] + cconst[0];
}

// ---------- launch ----------

extern "C" void kernel_launch(void* const* d_in, const int* in_sizes, int n_in,
                              void* d_out, int out_size, void* d_ws, size_t ws_size,
                              hipStream_t stream) {
    const float* x    = (const float*)d_in[0];
    const int*   eidx = (const int*)d_in[1];
    const float* mean = (const float*)d_in[3];
    const float* stdv = (const float*)d_in[4];
    const float* W1   = (const float*)d_in[5];
    const float* b1   = (const float*)d_in[6];
    const float* W2   = (const float*)d_in[7];
    const float* b2   = (const float*)d_in[8];
    const float* W3   = (const float*)d_in[9];
    const float* b3   = (const float*)d_in[10];
    const float* Wout = (const float*)d_in[11];
    const float* bout = (const float*)d_in[12];
    float* out = (float*)d_out;

    const int n = in_sizes[0] / IN_F;       // 50000
    const int E = in_sizes[1] / 2;          // 800000
    const int* srcv = eidx;
    const int* dstv = eidx + E;

    char* ws = (char*)d_ws;
    size_t off = 0;
    auto alloc = [&](size_t bytes) -> void* {
        void* p = ws + off;
        off = (off + bytes + 255) & ~(size_t)255;
        return p;
    };
    int nscanb = (n + 255) / 256;
    int*    deg    = (int*)alloc((size_t)n * 4);
    int*    fill   = (int*)alloc((size_t)n * 4);
    int*    rowoff = (int*)alloc(((size_t)n + 1) * 4);
    int*    bsum   = (int*)alloc((size_t)nscanb * 4);
    float*  dinv   = (float*)alloc((size_t)n * 4);
    int2*   ecw    = (int2*)alloc((size_t)E * 8);
    float*  rstd   = (float*)alloc(IN_F * 4);
    float*  wv     = (float*)alloc(HID_F * 4);
    float*  cconst = (float*)alloc(4);
    float*  zbuf   = (float*)alloc((size_t)n * 4);
    __half* bufA   = (__half*)alloc((size_t)n * HID_F * 2);   // fp16 GEMM out (gathered)
    float*  bufB   = (float*)alloc((size_t)n * HID_F * 4);    // fp32 h1 (GEMM2 input)

    hipMemsetAsync(deg, 0, (size_t)n * 4, stream);
    hipMemsetAsync(fill, 0, (size_t)n * 4, stream);

    prep_kernel<<<1, 128, 0, stream>>>(stdv, rstd, W3, Wout, b3, bout, wv, cconst);
    count_kernel<<<(E + 255) / 256, 256, 0, stream>>>(dstv, deg, E);
    dinv_kernel<<<(n + 255) / 256, 256, 0, stream>>>(deg, dinv, n);
    scan_p1_kernel<<<nscanb, 256, 0, stream>>>(deg, rowoff, bsum, n);
    scan_p2_kernel<<<1, 1024, 0, stream>>>(bsum, nscanb);
    scan_p3_kernel<<<nscanb, 256, 0, stream>>>(rowoff, bsum, n, E);
    scatter_kernel<<<(E + 255) / 256, 256, 0, stream>>>(srcv, dstv, rowoff, fill, dinv,
                                                        ecw, E);

    int gemm_grid = (n + 63) / 64;
    int prop_grid = (int)(((long)n * 64 + 255) / 256);

    // layer 1: GEMM (fused standardization, fp16 out) -> prop+b1+relu (fp32 out)
    gemm_kernel<<<gemm_grid, 256, 0, stream>>>(x, W1, mean, rstd, bufA, n, IN_F, 1);
    prop_kernel<<<prop_grid, 256, 0, stream>>>((const __half2*)bufA, rowoff, ecw, dinv,
                                               b1, bufB, n);
    // layer 2: GEMM (fp16 out) -> prop+b2+relu fused with dot(wv) -> scalar z
    gemm_kernel<<<gemm_grid, 256, 0, stream>>>(bufB, W2, nullptr, nullptr, bufA, n, HID_F, 0);
    prop_dot_kernel<<<prop_grid, 256, 0, stream>>>((const __half2*)bufA, rowoff, ecw, dinv,
                                                   b2, wv, zbuf, n);
    // layer 3 (folded): scalar prop over z
    prop_scalar_kernel<<<(n + 255) / 256, 256, 0, stream>>>(zbuf, rowoff, ecw, dinv,
                                                            cconst, out, n);
}

// Round 6
// 298.936 us; speedup vs baseline: 2.0348x; 1.0914x over previous
//
#include <hip/hip_runtime.h>
#include <hip/hip_fp16.h>

#define IN_F 128
#define HID_F 96

typedef _Float16 f16x8 __attribute__((ext_vector_type(8)));
typedef float f32x4 __attribute__((ext_vector_type(4)));

// ---------- small prep: rstd, folded wv = W3 @ Wout[:,1], c = b3.Wout[:,1] + bout[1] ----------

__global__ void prep_kernel(const float* __restrict__ stdv, float* __restrict__ rstd,
                            const float* __restrict__ W3, const float* __restrict__ Wout,
                            const float* __restrict__ b3, const float* __restrict__ bout,
                            float* __restrict__ wv, float* __restrict__ cconst) {
    int t = threadIdx.x;
    if (t < IN_F) rstd[t] = 1.0f / stdv[t];
    if (t < HID_F) {
        float s = 0.f;
        for (int j = 0; j < HID_F; ++j) s += W3[t * HID_F + j] * Wout[j * 2 + 1];
        wv[t] = s;
    }
    if (t == 0) {
        float s = 0.f;
        for (int j = 0; j < HID_F; ++j) s += b3[j] * Wout[j * 2 + 1];
        cconst[0] = s + bout[1];
    }
}

// ---------- W pre-swizzle into MFMA B-fragment order ----------
// Wsw[((c*6+t)*64+lane)*8+j] = (half)W[(c*32+(lane>>4)*8+j)*96 + t*16+(lane&15)]
__global__ void swizzleW_kernel(const float* __restrict__ W, __half* __restrict__ Wsw,
                                int total) {
    int idx = blockIdx.x * 256 + threadIdx.x;
    if (idx >= total) return;
    int j  = idx & 7;
    int ln = (idx >> 3) & 63;
    int ct = idx >> 9;
    int t = ct % 6, c = ct / 6;
    int k   = c * 32 + (ln >> 4) * 8 + j;
    int col = t * 16 + (ln & 15);
    Wsw[idx] = (__half)W[k * 96 + col];
}

// ---------- CSR build ----------

__global__ void count_kernel(const int* __restrict__ dst, int* __restrict__ deg, int E) {
    int i = blockIdx.x * blockDim.x + threadIdx.x;
    if (i < E) atomicAdd(&deg[dst[i]], 1);
}

__global__ void dinv_kernel(const int* __restrict__ deg, float* __restrict__ dinv, int n) {
    int i = blockIdx.x * blockDim.x + threadIdx.x;
    if (i < n) dinv[i] = rsqrtf((float)deg[i] + 1.0f);  // +1 self-loop
}

// ---------- device-wide exclusive scan of deg -> rowoff, 3 phases ----------
__global__ __launch_bounds__(256) void scan_p1_kernel(
        const int* __restrict__ cnt, int* __restrict__ rowoff,
        int* __restrict__ bsum, int n) {
    __shared__ int tmp[256];
    int t = threadIdx.x;
    int i = blockIdx.x * 256 + t;
    int v = (i < n) ? cnt[i] : 0;
    tmp[t] = v;
    __syncthreads();
#pragma unroll
    for (int off = 1; off < 256; off <<= 1) {
        int u = (t >= off) ? tmp[t - off] : 0;
        __syncthreads();
        tmp[t] += u;
        __syncthreads();
    }
    if (i < n) rowoff[i] = tmp[t] - v;
    if (t == 255) bsum[blockIdx.x] = tmp[255];
}

__global__ __launch_bounds__(1024) void scan_p2_kernel(int* __restrict__ bsum, int nb) {
    __shared__ int tmp[1024];
    int t = threadIdx.x;
    int v = (t < nb) ? bsum[t] : 0;
    tmp[t] = v;
    __syncthreads();
#pragma unroll
    for (int off = 1; off < 1024; off <<= 1) {
        int u = (t >= off) ? tmp[t - off] : 0;
        __syncthreads();
        tmp[t] += u;
        __syncthreads();
    }
    if (t < nb) bsum[t] = tmp[t] - v;
}

__global__ __launch_bounds__(256) void scan_p3_kernel(
        int* __restrict__ rowoff, const int* __restrict__ bsum, int n, int total) {
    int i = blockIdx.x * 256 + threadIdx.x;
    if (i < n) rowoff[i] += bsum[blockIdx.x];
    if (i == 0) rowoff[n] = total;
}

// packed edge record: .x = src node, .y = float bits of norm weight
__global__ void scatter_kernel(const int* __restrict__ srcv, const int* __restrict__ dstv,
                               const int* __restrict__ rowoff, int* __restrict__ fill,
                               const float* __restrict__ dinv,
                               int2* __restrict__ ecw, int E) {
    int i = blockIdx.x * blockDim.x + threadIdx.x;
    if (i < E) {
        int s = srcv[i], d = dstv[i];
        int pos = rowoff[d] + atomicAdd(&fill[d], 1);
        int2 r;
        r.x = s;
        r.y = __float_as_int(dinv[s] * dinv[d]);
        ecw[pos] = r;
    }
}

// ---------- MFMA fp16 GEMM: C[n][96](fp16) = A[n][K] @ W[K][96] ----------
// No LDS, no barriers. Block = 4 waves; wave owns 16 rows x 96 cols (6 MFMA acc tiles).
// A-fragments straight from global (each A element used exactly once);
// B-fragments from the pre-swizzled Wsw (one coalesced 16B load per lane per (c,t)).
// MODE 0: A fp32 + standardization fused into the fp16 convert. MODE 1: A fp16.

template<int MODE, int K>
__global__ __launch_bounds__(256) void gemm_mfma_kernel(
        const void* __restrict__ Ain, const __half* __restrict__ Wsw,
        const float* __restrict__ mean, const float* __restrict__ rstd,
        __half* __restrict__ C, int n) {
    constexpr int NCH = K / 32;
    int lane = threadIdx.x & 63;
    int wv_  = threadIdx.x >> 6;
    int m = lane & 15, q = lane >> 4;
    int node0 = blockIdx.x * 64 + wv_ * 16;
    int g = node0 + m;
    int gc = g < n ? g : n - 1;   // clamp: garbage rows computed, stores guarded

    f32x4 acc[6];
#pragma unroll
    for (int t = 0; t < 6; ++t) acc[t] = (f32x4){0.f, 0.f, 0.f, 0.f};

#pragma unroll
    for (int c = 0; c < NCH; ++c) {
        f16x8 a;
        if (MODE == 0) {
            const float* ap = (const float*)Ain + (long)gc * K + c * 32 + q * 8;
            float4 v0 = *(const float4*)ap;
            float4 v1 = *(const float4*)(ap + 4);
            float4 m0 = *(const float4*)(mean + c * 32 + q * 8);
            float4 m1 = *(const float4*)(mean + c * 32 + q * 8 + 4);
            float4 r0 = *(const float4*)(rstd + c * 32 + q * 8);
            float4 r1 = *(const float4*)(rstd + c * 32 + q * 8 + 4);
            a[0] = (_Float16)((v0.x - m0.x) * r0.x);
            a[1] = (_Float16)((v0.y - m0.y) * r0.y);
            a[2] = (_Float16)((v0.z - m0.z) * r0.z);
            a[3] = (_Float16)((v0.w - m0.w) * r0.w);
            a[4] = (_Float16)((v1.x - m1.x) * r1.x);
            a[5] = (_Float16)((v1.y - m1.y) * r1.y);
            a[6] = (_Float16)((v1.z - m1.z) * r1.z);
            a[7] = (_Float16)((v1.w - m1.w) * r1.w);
        } else {
            a = *(const f16x8*)((const __half*)Ain + (long)gc * K + c * 32 + q * 8);
        }
#pragma unroll
        for (int t = 0; t < 6; ++t) {
            f16x8 b = *(const f16x8*)(Wsw + (size_t)(((c * 6) + t) * 64 + lane) * 8);
            acc[t] = __builtin_amdgcn_mfma_f32_16x16x32_f16(a, b, acc[t], 0, 0, 0);
        }
    }
    // C/D layout: col = lane&15, row = (lane>>4)*4 + reg
#pragma unroll
    for (int t = 0; t < 6; ++t)
#pragma unroll
        for (int r = 0; r < 4; ++r) {
            int gr = node0 + q * 4 + r;
            if (gr < n) C[(long)gr * 96 + t * 16 + m] = (__half)acc[t][r];
        }
}

// ---------- pull-based prop (layer 1): wave per node, lane<48 holds half2 channel pair ----
// hin: fp16 rows [n][96]; hout: fp16 rows [n][96] (feeds MFMA GEMM2 directly)

__global__ __launch_bounds__(256) void prop_kernel(
        const __half2* __restrict__ hin, const int* __restrict__ rowoff,
        const int2* __restrict__ ecw,
        const float* __restrict__ dinv, const float* __restrict__ bias,
        __half2* __restrict__ hout, int n) {
    int wid = (blockIdx.x * blockDim.x + threadIdx.x) >> 6;
    int lane = threadIdx.x & 63;
    if (wid >= n) return;
    int e0 = rowoff[wid], e1 = rowoff[wid + 1];
    bool act = lane < 48;
    int li = act ? lane : 0;
    float ax = 0.f, ay = 0.f;
    int e = e0;
    for (; e + 8 <= e1; e += 8) {
        int2 c[8];
        __half2 g[8];
#pragma unroll
        for (int k = 0; k < 8; ++k) c[k] = ecw[e + k];
#pragma unroll
        for (int k = 0; k < 8; ++k) g[k] = hin[(long)c[k].x * 48 + li];
#pragma unroll
        for (int k = 0; k < 8; ++k) {
            float w = __int_as_float(c[k].y);
            float2 f = __half22float2(g[k]);
            ax += w * f.x; ay += w * f.y;
        }
    }
    for (; e < e1; ++e) {
        int2 c = ecw[e];
        float w = __int_as_float(c.y);
        float2 f = __half22float2(hin[(long)c.x * 48 + li]);
        ax += w * f.x; ay += w * f.y;
    }
    float ds = dinv[wid]; ds *= ds;
    float2 self = __half22float2(hin[(long)wid * 48 + li]);
    ax += ds * self.x; ay += ds * self.y;
    if (act) {
        float2 b = ((const float2*)bias)[li];
        hout[(long)wid * 48 + li] =
            __floats2half2_rn(fmaxf(ax + b.x, 0.f), fmaxf(ay + b.y, 0.f));
    }
}

// ---------- prop (layer 2) fused with z = relu(agg+b2) . wv : writes scalar z[node] ------

__global__ __launch_bounds__(256) void prop_dot_kernel(
        const __half2* __restrict__ hin, const int* __restrict__ rowoff,
        const int2* __restrict__ ecw,
        const float* __restrict__ dinv, const float* __restrict__ bias,
        const float* __restrict__ wv, float* __restrict__ z, int n) {
    int wid = (blockIdx.x * blockDim.x + threadIdx.x) >> 6;
    int lane = threadIdx.x & 63;
    if (wid >= n) return;
    int e0 = rowoff[wid], e1 = rowoff[wid + 1];
    bool act = lane < 48;
    int li = act ? lane : 0;
    float ax = 0.f, ay = 0.f;
    int e = e0;
    for (; e + 8 <= e1; e += 8) {
        int2 c[8];
        __half2 g[8];
#pragma unroll
        for (int k = 0; k < 8; ++k) c[k] = ecw[e + k];
#pragma unroll
        for (int k = 0; k < 8; ++k) g[k] = hin[(long)c[k].x * 48 + li];
#pragma unroll
        for (int k = 0; k < 8; ++k) {
            float w = __int_as_float(c[k].y);
            float2 f = __half22float2(g[k]);
            ax += w * f.x; ay += w * f.y;
        }
    }
    for (; e < e1; ++e) {
        int2 c = ecw[e];
        float w = __int_as_float(c.y);
        float2 f = __half22float2(hin[(long)c.x * 48 + li]);
        ax += w * f.x; ay += w * f.y;
    }
    float ds = dinv[wid]; ds *= ds;
    float2 self = __half22float2(hin[(long)wid * 48 + li]);
    ax += ds * self.x; ay += ds * self.y;
    float v = 0.f;
    if (act) {
        float2 b = ((const float2*)bias)[li];
        float2 wp = ((const float2*)wv)[li];
        v = fmaxf(ax + b.x, 0.f) * wp.x + fmaxf(ay + b.y, 0.f) * wp.y;
    }
#pragma unroll
    for (int off = 32; off; off >>= 1) v += __shfl_xor(v, off, 64);
    if (lane == 0) z[wid] = v;
}

// ---------- layer-3 prop over scalar z: out[d] = sum w[e]*z[col] + dinv2*z[d] + c ----------

__global__ __launch_bounds__(256) void prop_scalar_kernel(
        const float* __restrict__ z, const int* __restrict__ rowoff,
        const int2* __restrict__ ecw,
        const float* __restrict__ dinv, const float* __restrict__ cconst,
        float* __restrict__ out, int n) {
    int i = blockIdx.x * blockDim.x + threadIdx.x;
    if (i >= n) return;
    int e0 = rowoff[i], e1 = rowoff[i + 1];
    float s = 0.f;
    int e = e0;
    for (; e + 4 <= e1; e += 4) {
        int2 c0 = ecw[e + 0], c1 = ecw[e + 1], c2 = ecw[e + 2], c3 = ecw[e + 3];
        float z0 = z[c0.x], z1 = z[c1.x], z2 = z[c2.x], z3 = z[c3.x];
        s += __int_as_float(c0.y) * z0; s += __int_as_float(c1.y) * z1;
        s += __int_as_float(c2.y) * z2; s += __int_as_float(c3.y) * z3;
    }
    for (; e < e1; ++e) {
        int2 c = ecw[e];
        s += __int_as_float(c.y) * z[c.x];
    }
    float ds = dinv[i]; ds *= ds;
    out[i] = s + ds * z[i] + cconst[0];
}

// ---------- launch ----------

extern "C" void kernel_launch(void* const* d_in, const int* in_sizes, int n_in,
                              void* d_out, int out_size, void* d_ws, size_t ws_size,
                              hipStream_t stream) {
    const float* x    = (const float*)d_in[0];
    const int*   eidx = (const int*)d_in[1];
    const float* mean = (const float*)d_in[3];
    const float* stdv = (const float*)d_in[4];
    const float* W1   = (const float*)d_in[5];
    const float* b1   = (const float*)d_in[6];
    const float* W2   = (const float*)d_in[7];
    const float* b2   = (const float*)d_in[8];
    const float* W3   = (const float*)d_in[9];
    const float* b3   = (const float*)d_in[10];
    const float* Wout = (const float*)d_in[11];
    const float* bout = (const float*)d_in[12];
    float* out = (float*)d_out;

    const int n = in_sizes[0] / IN_F;       // 50000
    const int E = in_sizes[1] / 2;          // 800000
    const int* srcv = eidx;
    const int* dstv = eidx + E;

    char* ws = (char*)d_ws;
    size_t off = 0;
    auto alloc = [&](size_t bytes) -> void* {
        void* p = ws + off;
        off = (off + bytes + 255) & ~(size_t)255;
        return p;
    };
    int nscanb = (n + 255) / 256;
    const int SW1 = 4 * 6 * 64 * 8;         // W1 swizzled half count (K=128)
    const int SW2 = 3 * 6 * 64 * 8;         // W2 swizzled half count (K=96)
    int*    deg    = (int*)alloc((size_t)n * 4);
    int*    fill   = (int*)alloc((size_t)n * 4);
    int*    rowoff = (int*)alloc(((size_t)n + 1) * 4);
    int*    bsum   = (int*)alloc((size_t)nscanb * 4);
    float*  dinv   = (float*)alloc((size_t)n * 4);
    int2*   ecw    = (int2*)alloc((size_t)E * 8);
    float*  rstd   = (float*)alloc(IN_F * 4);
    float*  wv     = (float*)alloc(HID_F * 4);
    float*  cconst = (float*)alloc(4);
    float*  zbuf   = (float*)alloc((size_t)n * 4);
    __half* Wsw1   = (__half*)alloc((size_t)SW1 * 2);
    __half* Wsw2   = (__half*)alloc((size_t)SW2 * 2);
    __half* bufA   = (__half*)alloc((size_t)n * HID_F * 2);   // fp16 GEMM out (gathered)
    __half* bufB   = (__half*)alloc((size_t)n * HID_F * 2);   // fp16 h1 (GEMM2 input)

    hipMemsetAsync(deg, 0, (size_t)n * 4, stream);
    hipMemsetAsync(fill, 0, (size_t)n * 4, stream);

    prep_kernel<<<1, 128, 0, stream>>>(stdv, rstd, W3, Wout, b3, bout, wv, cconst);
    swizzleW_kernel<<<(SW1 + 255) / 256, 256, 0, stream>>>(W1, Wsw1, SW1);
    swizzleW_kernel<<<(SW2 + 255) / 256, 256, 0, stream>>>(W2, Wsw2, SW2);
    count_kernel<<<(E + 255) / 256, 256, 0, stream>>>(dstv, deg, E);
    dinv_kernel<<<(n + 255) / 256, 256, 0, stream>>>(deg, dinv, n);
    scan_p1_kernel<<<nscanb, 256, 0, stream>>>(deg, rowoff, bsum, n);
    scan_p2_kernel<<<1, 1024, 0, stream>>>(bsum, nscanb);
    scan_p3_kernel<<<nscanb, 256, 0, stream>>>(rowoff, bsum, n, E);
    scatter_kernel<<<(E + 255) / 256, 256, 0, stream>>>(srcv, dstv, rowoff, fill, dinv,
                                                        ecw, E);

    int gemm_grid = (n + 63) / 64;
    int prop_grid = (int)(((long)n * 64 + 255) / 256);

    // layer 1: MFMA GEMM (fused standardization, fp16 out) -> prop+b1+relu (fp16 out)
    gemm_mfma_kernel<0, IN_F><<<gemm_grid, 256, 0, stream>>>(x, Wsw1, mean, rstd, bufA, n);
    prop_kernel<<<prop_grid, 256, 0, stream>>>((const __half2*)bufA, rowoff, ecw, dinv,
                                               b1, (__half2*)bufB, n);
    // layer 2: MFMA GEMM (fp16 in/out) -> prop+b2+relu fused with dot(wv) -> scalar z
    gemm_mfma_kernel<1, HID_F><<<gemm_grid, 256, 0, stream>>>(bufB, Wsw2, nullptr, nullptr,
                                                              bufA, n);
    prop_dot_kernel<<<prop_grid, 256, 0, stream>>>((const __half2*)bufA, rowoff, ecw, dinv,
                                                   b2, wv, zbuf, n);
    // layer 3 (folded): scalar prop over z
    prop_scalar_kernel<<<(n + 255) / 256, 256, 0, stream>>>(zbuf, rowoff, ecw, dinv,
                                                            cconst, out, n);
}